// Round 9
// baseline (99.335 us; speedup 1.0000x reference)
//
#include <hip/hip_runtime.h>
#include <float.h>

// VectorQuantizer on MI355X — bit-exact numpy-f32 replication (R4-proven numerics).
//
// Ladder: R4 274us -> R7 97us (s_load e-rows + 4 waves/SIMD). R7/R8 post-mortem:
// allocator refuses to keep xv[64] in VGPRs (remats x-loads in the k-loop;
// waves_per_eu(4,4) no effect) -> VALU stream is 2.1x the fma floor.
// R9: pixel rows live in TRANSPOSED LDS (xlds[d][pixel], conflict-free reads:
// consecutive lanes -> consecutive addresses), k-loop per-thread state ~20 VGPRs.
// e-rows stay scalar (s_load, proven R7). Anti-LICM opaque offset stops the
// compiler hoisting the 64 kk-invariant ds_reads back into registers (would
// recreate the pressure -> scratch spill, R6's failure mode).
#pragma clang fp contract(off)

#define K_EMB   512
#define D_EMB   64
#define Q_ELEMS 4194304   // 64 * 64 * 32 * 32
#define NBLK    1024      // 64 pixels per block, 4 waves split K

// numpy pairwise_sum tree for 64 elements (summing pre-rounded squares).
// Incremental form reading from LDS: 8 accumulators, same order as np.
__device__ __forceinline__ float np_sumsq64_lds(const float* __restrict__ xl,
                                                int lane) {
    float r[8];
    #pragma unroll
    for (int j = 0; j < 8; ++j) {
        float v = xl[j * 64 + lane];
        r[j] = v * v;
    }
    #pragma unroll
    for (int i = 8; i < 64; i += 8) {
        #pragma unroll
        for (int j = 0; j < 8; ++j) {
            float v = xl[(i + j) * 64 + lane];
            float s = v * v;
            r[j] = r[j] + s;
        }
    }
    return ((r[0] + r[1]) + (r[2] + r[3])) + ((r[4] + r[5]) + (r[6] + r[7]));
}

// ---------------- kernel 1: t2[k] = np-f32 sum(emb_k^2) ----------------
__global__ __launch_bounds__(256) void vq_prep(const float* __restrict__ emb,
                                               float* __restrict__ t2) {
    int k = blockIdx.x * 256 + threadIdx.x;
    if (k < K_EMB) {
        const float* ep = emb + (k << 6);
        float r[8];
        #pragma unroll
        for (int j = 0; j < 8; ++j) r[j] = ep[j] * ep[j];
        #pragma unroll
        for (int i = 8; i < 64; i += 8) {
            #pragma unroll
            for (int j = 0; j < 8; ++j) {
                float s = ep[i + j] * ep[i + j];
                r[j] = r[j] + s;
            }
        }
        t2[k] = ((r[0] + r[1]) + (r[2] + r[3])) + ((r[4] + r[5]) + (r[6] + r[7]));
    }
}

// ---------------- kernel 2: main VQ ----------------
__global__ __launch_bounds__(256) void vq_main(const float* __restrict__ x,
                                               const float* __restrict__ emb,
                                               const float* __restrict__ t2,
                                               float* __restrict__ out_q,
                                               float* __restrict__ out_idx,
                                               float* __restrict__ partial) {
    const int tid  = threadIdx.x;
    const int lane = tid & 63;
    const int wave = __builtin_amdgcn_readfirstlane(tid >> 6);  // uniform

    const int n  = blockIdx.x * 64 + lane;           // pixel (same 64 per block)
    const int b  = n >> 10;                          // uniform per block
    const int hw = n & 1023;
    const float* __restrict__ xp = x + b * 65536 + hw;

    __shared__ float xlds[D_EMB * 64];               // [d][pixel], 16 KB
    __shared__ float s_best[4][64];
    __shared__ int   s_bi[4][64];

    // cooperative transposed staging: wave w stages d = 16w .. 16w+15.
    // Global: lanes 0..63 -> consecutive hw (coalesced 256B). LDS write:
    // consecutive lanes -> consecutive addresses (2-way bank alias = free).
    #pragma unroll
    for (int dd = 0; dd < 16; ++dd) {
        const int d = wave * 16 + dd;
        xlds[d * 64 + lane] = xp[d * 1024];
    }
    __syncthreads();

    const float t1 = np_sumsq64_lds(xlds, lane);     // numpy tree, f32

    float best = FLT_MAX;
    int   bi   = 0;
    const int k0 = wave << 7;                        // this wave's 128 codes
    for (int kk = 0; kk < 128; kk += 4) {
        const int k = k0 + kk;
        const float* __restrict__ e0 = emb + ((k + 0) << 6);  // uniform -> s_load
        const float* __restrict__ e1 = emb + ((k + 1) << 6);
        const float* __restrict__ e2 = emb + ((k + 2) << 6);
        const float* __restrict__ e3 = emb + ((k + 3) << 6);

        // anti-LICM: opaque byte offset, redefined every iteration, so the 64
        // ds_reads below cannot be hoisted out of the kk-loop (would need 64
        // VGPRs -> spill). Address folds to ds_read_b32 ... offset:d*256.
        int xoff = lane << 2;
        asm volatile("" : "+v"(xoff));
        const float* __restrict__ xl = (const float*)((const char*)xlds + xoff);

        float a0 = 0.f, a1 = 0.f, a2 = 0.f, a3 = 0.f;
        #pragma unroll
        for (int d = 0; d < D_EMB; ++d) {
            const float xd = xl[d * 64];             // conflict-free broadcast row
            a0 = fmaf(xd, e0[d], a0);                // BLAS chain: 1 rounding/step
            a1 = fmaf(xd, e1[d], a1);
            a2 = fmaf(xd, e2[d], a2);
            a3 = fmaf(xd, e3[d], a3);
        }
        // dist = fl32( fl32(t1+t2) - 2*d ): 2*d exact -> fmaf = same rounding
        float X0 = t1 + t2[k + 0];
        float X1 = t1 + t2[k + 1];
        float X2 = t1 + t2[k + 2];
        float X3 = t1 + t2[k + 3];
        float d0 = fmaf(-2.f, a0, X0);
        float d1 = fmaf(-2.f, a1, X1);
        float d2 = fmaf(-2.f, a2, X2);
        float d3 = fmaf(-2.f, a3, X3);
        if (d0 < best) { best = d0; bi = k + 0; }    // strict <, ascending k
        if (d1 < best) { best = d1; bi = k + 1; }
        if (d2 < best) { best = d2; bi = k + 2; }
        if (d3 < best) { best = d3; bi = k + 3; }
    }

    // cross-wave argmin merge (ascending wave == ascending k; strict <)
    s_best[wave][lane] = best;
    s_bi[wave][lane]   = bi;
    __syncthreads();
    if (wave != 0) return;

    #pragma unroll
    for (int w = 1; w < 4; ++w) {
        float dw = s_best[w][lane];
        if (dw < best) { best = dw; bi = s_bi[w][lane]; }
    }

    // epilogue (wave 0): gather winning embedding, write quantized, loss partial
    const float4* __restrict__ eq = (const float4*)(emb + (bi << 6));
    float* __restrict__ qp = out_q + b * 65536 + hw;
    float acc = 0.f;
    #pragma unroll
    for (int j = 0; j < 16; ++j) {
        float4 q = eq[j];
        const int d = j * 4;
        float x0 = xlds[(d + 0) * 64 + lane];
        float x1 = xlds[(d + 1) * 64 + lane];
        float x2 = xlds[(d + 2) * 64 + lane];
        float x3 = xlds[(d + 3) * 64 + lane];
        float f0 = q.x - x0;
        float f1 = q.y - x1;
        float f2 = q.z - x2;
        float f3 = q.w - x3;
        acc = fmaf(f0, f0, acc);
        acc = fmaf(f1, f1, acc);
        acc = fmaf(f2, f2, acc);
        acc = fmaf(f3, f3, acc);
        qp[(d + 0) * 1024] = q.x;
        qp[(d + 1) * 1024] = q.y;
        qp[(d + 2) * 1024] = q.z;
        qp[(d + 3) * 1024] = q.w;
    }
    out_idx[n] = (float)bi;

    // wave-internal loss reduce
    #pragma unroll
    for (int off = 32; off > 0; off >>= 1) acc += __shfl_down(acc, off);
    if (lane == 0) partial[blockIdx.x] = acc;
}

// ---------------- kernel 3: finalize loss over 1024 partials ----------------
__global__ __launch_bounds__(256) void vq_loss(const float* __restrict__ partial,
                                               float* __restrict__ loss) {
    const int t = threadIdx.x;
    float v = (partial[t] + partial[t + 256]) + (partial[t + 512] + partial[t + 768]);
    #pragma unroll
    for (int off = 32; off > 0; off >>= 1) v += __shfl_down(v, off);
    __shared__ float red[4];
    if ((t & 63) == 0) red[t >> 6] = v;
    __syncthreads();
    if (t == 0)
        loss[0] = 1.25f * ((red[0] + red[1]) + (red[2] + red[3])) / (float)Q_ELEMS;
}

extern "C" void kernel_launch(void* const* d_in, const int* in_sizes, int n_in,
                              void* d_out, int out_size, void* d_ws, size_t ws_size,
                              hipStream_t stream) {
    const float* x   = (const float*)d_in[0];   // [64,64,32,32] NCHW
    const float* emb = (const float*)d_in[1];   // [512,64]

    float* out_q    = (float*)d_out;                // [4194304]
    float* out_loss = (float*)d_out + Q_ELEMS;      // [1]
    float* out_idx  = (float*)d_out + Q_ELEMS + 1;  // [65536] as float

    float* t2      = (float*)d_ws;       // 512 floats
    float* partial = t2 + K_EMB;         // 1024 floats

    vq_prep<<<2, 256, 0, stream>>>(emb, t2);
    vq_main<<<NBLK, 256, 0, stream>>>(x, emb, t2, out_q, out_idx, partial);
    vq_loss<<<1, 256, 0, stream>>>(partial, out_loss);
}